// Round 1
// baseline (160.199 us; speedup 1.0000x reference)
//
#include <hip/hip_runtime.h>
#include <hip/hip_bf16.h>

// Problem: B=4, S=128, H=768, OUT*TAG=96
// scores[b,i,j,o] = sum_k relu(head[b,i,k] + tail[b,j,k] + b1[k]) * W2[k,o] + b2[o]
//   head = x @ W1[:768], tail = x @ W1[768:]
// Strategy: bf16 MFMA everywhere. ws holds bf16 xb, W1T, W2T, head, tailb.

typedef __bf16 bf16x8 __attribute__((ext_vector_type(8)));
typedef float f32x4 __attribute__((ext_vector_type(4)));

#define S_   128
#define H_   768
#define K3   2304   // 3*H
#define NOUT 96

__device__ __forceinline__ unsigned short f2bf(float f) {
    union { __bf16 b; unsigned short u; } c;
    c.b = (__bf16)f;   // RNE
    return c.u;
}

__device__ __forceinline__ void gload_lds16(const unsigned short* g, unsigned short* l) {
    __builtin_amdgcn_global_load_lds(
        (const __attribute__((address_space(1))) void*)g,
        (__attribute__((address_space(3))) void*)l,
        16, 0, 0);
}

// ---------- prep: x fp32 -> bf16 (layout unchanged, [512][768]) ----------
__global__ void k_cvt_x(const float4* __restrict__ x, ushort4* __restrict__ xb) {
    int t = blockIdx.x * 256 + threadIdx.x;   // 98304 threads, exact
    float4 v = x[t];
    ushort4 o;
    o.x = f2bf(v.x); o.y = f2bf(v.y); o.z = f2bf(v.z); o.w = f2bf(v.w);
    xb[t] = o;
}

// ---------- prep: transpose fp32 [R][C] -> bf16 [C][R] (dims multiple of 32) ----------
__global__ void k_transpose(const float* __restrict__ src, unsigned short* __restrict__ dst,
                            int R, int C, long srcZ, long dstZ) {
    src += (long)blockIdx.z * srcZ;
    dst += (long)blockIdx.z * dstZ;
    __shared__ float tile[32][33];
    int c0 = blockIdx.x * 32, r0 = blockIdx.y * 32;
    int row = threadIdx.x >> 3;          // 0..31
    int c4  = (threadIdx.x & 7) * 4;     // 0..28
    float4 v = *(const float4*)(src + (size_t)(r0 + row) * C + c0 + c4);
    tile[row][c4 + 0] = v.x; tile[row][c4 + 1] = v.y;
    tile[row][c4 + 2] = v.z; tile[row][c4 + 3] = v.w;
    __syncthreads();
    ushort4 o;
    o.x = f2bf(tile[c4 + 0][row]); o.y = f2bf(tile[c4 + 1][row]);
    o.z = f2bf(tile[c4 + 2][row]); o.w = f2bf(tile[c4 + 3][row]);
    *(ushort4*)(dst + (size_t)(c0 + row) * R + r0 + c4) = o;
}

// ---------- GEMM1: [512 x 768] @ W1T^T -> head (cols 0..2303), tailb (+b1, cols 2304..4607) ----------
// out[m][c] = sum_h xb[m][h] * w1t[c][h];  stored bf16 row-major [512][2304] each.
__global__ __launch_bounds__(256) void k_gemm1(
        const unsigned short* __restrict__ xb,     // [512][768] bf16
        const unsigned short* __restrict__ w1t,    // [4608][768] bf16
        const float* __restrict__ b1,              // [2304]
        unsigned short* __restrict__ headb,        // [512][2304] bf16
        unsigned short* __restrict__ tailb) {      // [512][2304] bf16
    __shared__ unsigned short As[128 * 32];
    __shared__ unsigned short Bs[128 * 32];
    const int tid = threadIdx.x;
    const int l = tid & 63, w = tid >> 6;
    const int m0 = blockIdx.y * 128;
    const int n0 = blockIdx.x * 128;
    const int wr = (w >> 1) * 64, wc = (w & 1) * 64;
    const int lr = l & 15, lk = (l >> 4) * 8;
    f32x4 acc[4][4] = {};

    for (int kt = 0; kt < H_; kt += 32) {
#pragma unroll
        for (int p = 0; p < 2; ++p) {
            int idx = p * 256 + tid;
            int row = idx >> 2, seg = (idx & 3) * 8;
            gload_lds16(xb  + (size_t)(m0 + row) * H_ + kt + seg, As + idx * 8);
            gload_lds16(w1t + (size_t)(n0 + row) * H_ + kt + seg, Bs + idx * 8);
        }
        asm volatile("s_waitcnt vmcnt(0)" ::: "memory");
        __syncthreads();
        bf16x8 af[4], bfr[4];
#pragma unroll
        for (int i = 0; i < 4; i++) af[i]  = *(const bf16x8*)(As + (wr + i * 16 + lr) * 32 + lk);
#pragma unroll
        for (int j = 0; j < 4; j++) bfr[j] = *(const bf16x8*)(Bs + (wc + j * 16 + lr) * 32 + lk);
#pragma unroll
        for (int i = 0; i < 4; i++)
#pragma unroll
            for (int j = 0; j < 4; j++)
                acc[i][j] = __builtin_amdgcn_mfma_f32_16x16x32_bf16(af[i], bfr[j], acc[i][j], 0, 0, 0);
        __syncthreads();
    }

    const bool tailblk = (n0 >= K3);
    unsigned short* dst = tailblk ? tailb : headb;
    const int nloc = n0 - (tailblk ? K3 : 0);
    const int lv = (l >> 4) * 4;
#pragma unroll
    for (int j = 0; j < 4; j++) {
        int c = nloc + wc + j * 16 + lr;
        float bias = tailblk ? b1[c] : 0.0f;
#pragma unroll
        for (int i = 0; i < 4; i++) {
            int mrow = m0 + wr + i * 16 + lv;
#pragma unroll
            for (int e = 0; e < 4; e++)
                dst[(size_t)(mrow + e) * K3 + c] = f2bf(acc[i][j][e] + bias);
        }
    }
}

// ---------- main: per (b, 16 i's, 16 j's): relu(head_i + tailb_j) @ W2 + b2 ----------
__device__ __forceinline__ bf16x8 form8(uint4 h, uint4 t) {
    union { uint4 q; unsigned short s[8]; } H, T;
    H.q = h; T.q = t;
    bf16x8 r;
#pragma unroll
    for (int e = 0; e < 8; e++) {
        float hv = __uint_as_float((unsigned)H.s[e] << 16);
        float tv = __uint_as_float((unsigned)T.s[e] << 16);
        r[e] = (__bf16)fmaxf(hv + tv, 0.0f);
    }
    return r;
}

__global__ __launch_bounds__(512) void k_pair(
        const unsigned short* __restrict__ headb,  // [4*128][2304] bf16
        const unsigned short* __restrict__ tailb,  // [4*128][2304] bf16
        const unsigned short* __restrict__ w2t,    // [96][2304] bf16
        const float* __restrict__ b2,              // [96]
        float* __restrict__ out) {                 // [4][128][128][96] fp32
    const int tid = threadIdx.x;
    const int w = tid >> 6, l = tid & 63;
    const int lr = l & 15, lk = (l >> 4) * 8;
    const int b = blockIdx.z, i0 = blockIdx.y * 16, j0 = blockIdx.x * 16;

    const unsigned short* Hp = headb + (size_t)(b * S_ + i0 + 2 * w) * K3;   // 2 rows per wave
    const unsigned short* Tp = tailb + (size_t)(b * S_ + j0 + lr) * K3;      // per-lane j row

    f32x4 acc[2][6] = {};
    float b2v[6];
#pragma unroll
    for (int f = 0; f < 6; f++) b2v[f] = b2[f * 16 + lr];

    uint4 t8  = *(const uint4*)(Tp + lk);
    uint4 h8a = *(const uint4*)(Hp + lk);
    uint4 h8b = *(const uint4*)(Hp + K3 + lk);

    for (int kc = 0; kc < K3; kc += 32) {
        bf16x8 bfr[6];
#pragma unroll
        for (int f = 0; f < 6; f++)
            bfr[f] = *(const bf16x8*)(w2t + (size_t)(f * 16 + lr) * K3 + kc + lk);
        int kn = (kc + 32 < K3) ? kc + 32 : kc;
        uint4 t8n  = *(const uint4*)(Tp + kn + lk);
        uint4 h8an = *(const uint4*)(Hp + kn + lk);
        uint4 h8bn = *(const uint4*)(Hp + K3 + kn + lk);

        bf16x8 a0 = form8(h8a, t8);
        bf16x8 a1 = form8(h8b, t8);
#pragma unroll
        for (int f = 0; f < 6; f++) {
            acc[0][f] = __builtin_amdgcn_mfma_f32_16x16x32_bf16(a0, bfr[f], acc[0][f], 0, 0, 0);
            acc[1][f] = __builtin_amdgcn_mfma_f32_16x16x32_bf16(a1, bfr[f], acc[1][f], 0, 0, 0);
        }
        t8 = t8n; h8a = h8an; h8b = h8bn;
    }

    float* O = out + ((size_t)(b * S_ + i0 + 2 * w) * S_ + j0) * NOUT;
#pragma unroll
    for (int q = 0; q < 2; q++)
#pragma unroll
        for (int f = 0; f < 6; f++)
#pragma unroll
            for (int e = 0; e < 4; e++) {
                int j = (l >> 4) * 4 + e;
                O[(size_t)q * S_ * NOUT + (size_t)j * NOUT + f * 16 + lr] = acc[q][f][e] + b2v[f];
            }
}

extern "C" void kernel_launch(void* const* d_in, const int* in_sizes, int n_in,
                              void* d_out, int out_size, void* d_ws, size_t ws_size,
                              hipStream_t stream) {
    const float* x  = (const float*)d_in[0];   // [4][128][768]
    const float* W1 = (const float*)d_in[1];   // [1536][2304]
    const float* b1 = (const float*)d_in[2];   // [2304]
    const float* W2 = (const float*)d_in[3];   // [2304][96]
    const float* b2 = (const float*)d_in[4];   // [96]
    float* out = (float*)d_out;

    char* ws = (char*)d_ws;
    unsigned short* xb    = (unsigned short*)(ws);              //  512*768
    unsigned short* w1t   = (unsigned short*)(ws +   786432);   // 4608*768
    unsigned short* w2t   = (unsigned short*)(ws +  7864320);   //   96*2304
    unsigned short* headb = (unsigned short*)(ws +  8306688);   //  512*2304
    unsigned short* tailb = (unsigned short*)(ws + 10665984);   //  512*2304
    // total ws use: 13,025,280 bytes

    hipLaunchKernelGGL(k_cvt_x, dim3(384), dim3(256), 0, stream,
                       (const float4*)x, (ushort4*)xb);
    hipLaunchKernelGGL(k_transpose, dim3(72, 24, 2), dim3(256), 0, stream,
                       W1, w1t, H_, K3, (long)H_ * K3, (long)K3 * H_);
    hipLaunchKernelGGL(k_transpose, dim3(3, 72, 1), dim3(256), 0, stream,
                       W2, w2t, K3, NOUT, 0L, 0L);
    hipLaunchKernelGGL(k_gemm1, dim3(36, 4), dim3(256), 0, stream,
                       xb, w1t, b1, headb, tailb);
    hipLaunchKernelGGL(k_pair, dim3(8, 8, 4), dim3(512), 0, stream,
                       headb, tailb, w2t, b2, out);
}

// Round 4
// 87.792 us; speedup vs baseline: 1.8248x; 1.8248x over previous
//
#include <hip/hip_runtime.h>
#include <hip/hip_bf16.h>

// Problem: B=4, S=128, H=768, OUT*TAG=96
// scores[b,i,j,o] = sum_k relu(head[b,i,k] + tail[b,j,k] + b1[k]) * W2[k,o] + b2[o]
//   head = x @ W1[:768], tail = x @ W1[768:]
// R4: R3 structure with the k_pack_w2 copy-width bug fixed (ushort4 8B -> uint4 16B).

typedef __bf16 bf16x8 __attribute__((ext_vector_type(8)));
typedef float f32x4 __attribute__((ext_vector_type(4)));

#define S_   128
#define H_   768
#define K3   2304   // 3*H
#define NOUT 96
#define NKC  72     // K3/32 k-chunks

__device__ __forceinline__ unsigned short f2bf(float f) {
    union { __bf16 b; unsigned short u; } c;
    c.b = (__bf16)f;   // RNE
    return c.u;
}

__device__ __forceinline__ void gload_lds16(const unsigned short* g, unsigned short* l) {
    __builtin_amdgcn_global_load_lds(
        (const __attribute__((address_space(1))) void*)g,
        (__attribute__((address_space(3))) void*)l,
        16, 0, 0);
}

// ---------- prep: x fp32 -> bf16 (layout unchanged, [512][768]) ----------
__global__ void k_cvt_x(const float4* __restrict__ x, ushort4* __restrict__ xb) {
    int t = blockIdx.x * 256 + threadIdx.x;   // 98304 threads, exact
    float4 v = x[t];
    ushort4 o;
    o.x = f2bf(v.x); o.y = f2bf(v.y); o.z = f2bf(v.z); o.w = f2bf(v.w);
    xb[t] = o;
}

// ---------- prep: transpose fp32 [R][C] -> bf16 [C][R] (dims multiple of 32) ----------
__global__ void k_transpose(const float* __restrict__ src, unsigned short* __restrict__ dst,
                            int R, int C, long srcZ, long dstZ) {
    src += (long)blockIdx.z * srcZ;
    dst += (long)blockIdx.z * dstZ;
    __shared__ float tile[32][33];
    int c0 = blockIdx.x * 32, r0 = blockIdx.y * 32;
    int row = threadIdx.x >> 3;          // 0..31
    int c4  = (threadIdx.x & 7) * 4;     // 0..28
    float4 v = *(const float4*)(src + (size_t)(r0 + row) * C + c0 + c4);
    tile[row][c4 + 0] = v.x; tile[row][c4 + 1] = v.y;
    tile[row][c4 + 2] = v.z; tile[row][c4 + 3] = v.w;
    __syncthreads();
    ushort4 o;
    o.x = f2bf(tile[c4 + 0][row]); o.y = f2bf(tile[c4 + 1][row]);
    o.z = f2bf(tile[c4 + 2][row]); o.w = f2bf(tile[c4 + 3][row]);
    *(ushort4*)(dst + (size_t)(c0 + row) * R + r0 + c4) = o;
}

// ---------- prep: pack W2T bf16 [96][2304] into fragment order [72][6][64][8] ----------
// frag elem(kc,f,l,e) = W2T[f*16 + (l&15)][kc*32 + (l>>4)*8 + e]
__global__ void k_pack_w2(const unsigned short* __restrict__ w2t,
                          unsigned short* __restrict__ w2f) {
    int t = blockIdx.x * 256 + threadIdx.x;   // 27648 threads exact (108 blocks)
    int l = t & 63, f = (t >> 6) % 6, kc = t / 384;
    const unsigned short* src = w2t + (size_t)(f * 16 + (l & 15)) * K3 + kc * 32 + (l >> 4) * 8;
    // 8 ushorts = 16 bytes per fragment lane slot (was ushort4=8B: the R2/R3 bug)
    *(uint4*)(w2f + (size_t)t * 8) = *(const uint4*)src;
}

// ---------- GEMM1 (R1-verbatim): head -> headb, tail+b1 -> tailb, both row-major ----------
__global__ __launch_bounds__(256) void k_gemm1(
        const unsigned short* __restrict__ xb,     // [512][768] bf16
        const unsigned short* __restrict__ w1t,    // [4608][768] bf16
        const float* __restrict__ b1,              // [2304]
        unsigned short* __restrict__ headb,        // [512][2304] bf16
        unsigned short* __restrict__ tailb) {      // [512][2304] bf16
    __shared__ unsigned short As[128 * 32];
    __shared__ unsigned short Bs[128 * 32];
    const int tid = threadIdx.x;
    const int l = tid & 63, w = tid >> 6;
    const int m0 = blockIdx.y * 128;
    const int n0 = blockIdx.x * 128;
    const int wr = (w >> 1) * 64, wc = (w & 1) * 64;
    const int lr = l & 15, lk = (l >> 4) * 8;
    f32x4 acc[4][4] = {};

    for (int kt = 0; kt < H_; kt += 32) {
#pragma unroll
        for (int p = 0; p < 2; ++p) {
            int idx = p * 256 + tid;
            int row = idx >> 2, seg = (idx & 3) * 8;
            gload_lds16(xb  + (size_t)(m0 + row) * H_ + kt + seg, As + idx * 8);
            gload_lds16(w1t + (size_t)(n0 + row) * H_ + kt + seg, Bs + idx * 8);
        }
        asm volatile("s_waitcnt vmcnt(0)" ::: "memory");
        __syncthreads();
        bf16x8 af[4], bfr[4];
#pragma unroll
        for (int i = 0; i < 4; i++) af[i]  = *(const bf16x8*)(As + (wr + i * 16 + lr) * 32 + lk);
#pragma unroll
        for (int j = 0; j < 4; j++) bfr[j] = *(const bf16x8*)(Bs + (wc + j * 16 + lr) * 32 + lk);
#pragma unroll
        for (int i = 0; i < 4; i++)
#pragma unroll
            for (int j = 0; j < 4; j++)
                acc[i][j] = __builtin_amdgcn_mfma_f32_16x16x32_bf16(af[i], bfr[j], acc[i][j], 0, 0, 0);
        __syncthreads();
    }

    const bool tailblk = (n0 >= K3);
    unsigned short* dst = tailblk ? tailb : headb;
    const int nloc = n0 - (tailblk ? K3 : 0);
    const int lv = (l >> 4) * 4;
#pragma unroll
    for (int j = 0; j < 4; j++) {
        int c = nloc + wc + j * 16 + lr;
        float bias = tailblk ? b1[c] : 0.0f;
#pragma unroll
        for (int i = 0; i < 4; i++) {
            int mrow = m0 + wr + i * 16 + lv;
#pragma unroll
            for (int e = 0; e < 4; e++)
                dst[(size_t)(mrow + e) * K3 + c] = f2bf(acc[i][j][e] + bias);
        }
    }
}

// ---------- main pair kernel ----------
// 256 thr (4 waves), tile 8i x 16j. Wave w owns i = i0+2w, i0+2w+1.
// W2 frags: reg-staged LDS double buffer (load chunk t+1 early, ds_write after MFMA,
// one barrier per iter). Tail/head: per-lane global loads with depth-1 prefetch.
__device__ __forceinline__ bf16x8 form8(uint4 h, uint4 t) {
    union { uint4 q; unsigned short s[8]; } H, T;
    H.q = h; T.q = t;
    bf16x8 r;
#pragma unroll
    for (int e = 0; e < 8; e++) {
        float hv = __uint_as_float((unsigned)H.s[e] << 16);
        float tv = __uint_as_float((unsigned)T.s[e] << 16);
        r[e] = (__bf16)fmaxf(hv + tv, 0.0f);
    }
    return r;
}

__global__ __launch_bounds__(256) void k_pair(
        const unsigned short* __restrict__ headb,  // [512][2304] bf16
        const unsigned short* __restrict__ tailb,  // [512][2304] bf16
        const unsigned short* __restrict__ w2f,    // [72][6][64][8] bf16 frag order
        const float* __restrict__ b2,              // [96]
        float* __restrict__ out) {                 // [4][128][128][96] fp32
    __shared__ __align__(16) unsigned short lds[2][3072];   // 6KB per buf (one W2 k-chunk)

    const int tid = threadIdx.x;
    const int w = tid >> 6, l = tid & 63;
    const int lr = l & 15, lkq = l >> 4;
    const int lkoff = lkq * 8;
    const int jb = blockIdx.x;     // 0..7
    const int ig = blockIdx.y;     // 0..15
    const int b  = blockIdx.z;     // 0..3
    const int i0 = ig * 8;
    const bool lo = (tid < 128);

    const unsigned short* Hp = headb + (size_t)(b * S_ + i0 + 2 * w) * K3;
    const unsigned short* Tp = tailb + (size_t)(b * S_ + jb * 16 + lr) * K3;

    f32x4 acc[2][6] = {};
    float b2v[6];
#pragma unroll
    for (int f = 0; f < 6; f++) b2v[f] = b2[f * 16 + lr];

    // prologue: stage chunk 0 into buf 0
    {
        uint4 s0 = *(const uint4*)(w2f + tid * 8);
        uint4 s1 = lo ? *(const uint4*)(w2f + 2048 + tid * 8) : uint4{0, 0, 0, 0};
        *(uint4*)(&lds[0][tid * 8]) = s0;
        if (lo) *(uint4*)(&lds[0][2048 + tid * 8]) = s1;
    }

    uint4 t8  = *(const uint4*)(Tp + lkoff);
    uint4 h8a = *(const uint4*)(Hp + lkoff);
    uint4 h8b = *(const uint4*)(Hp + K3 + lkoff);

    __syncthreads();

    int buf = 0;
    for (int t = 0; t < NKC; ++t) {
        // issue next-chunk loads early (full iter of latency to hide)
        uint4 n0 = {0, 0, 0, 0}, n1 = {0, 0, 0, 0};
        if (t < NKC - 1) {
            const unsigned short* wsrc = w2f + (size_t)(t + 1) * 3072;
            n0 = *(const uint4*)(wsrc + tid * 8);
            if (lo) n1 = *(const uint4*)(wsrc + 2048 + tid * 8);
        }
        int kn = (t < NKC - 1) ? (t + 1) * 32 : t * 32;
        uint4 t8n  = *(const uint4*)(Tp + kn + lkoff);
        uint4 h8an = *(const uint4*)(Hp + kn + lkoff);
        uint4 h8bn = *(const uint4*)(Hp + K3 + kn + lkoff);

        bf16x8 bfr[6];
#pragma unroll
        for (int f = 0; f < 6; f++)
            bfr[f] = *(const bf16x8*)(&lds[buf][f * 512 + l * 8]);

        bf16x8 a0 = form8(h8a, t8);
        bf16x8 a1 = form8(h8b, t8);
#pragma unroll
        for (int f = 0; f < 6; f++) {
            acc[0][f] = __builtin_amdgcn_mfma_f32_16x16x32_bf16(a0, bfr[f], acc[0][f], 0, 0, 0);
            acc[1][f] = __builtin_amdgcn_mfma_f32_16x16x32_bf16(a1, bfr[f], acc[1][f], 0, 0, 0);
        }

        // write next chunk into the other buffer (safe: nobody reads buf^1 until
        // after the barrier below)
        if (t < NKC - 1) {
            *(uint4*)(&lds[buf ^ 1][tid * 8]) = n0;
            if (lo) *(uint4*)(&lds[buf ^ 1][2048 + tid * 8]) = n1;
        }
        t8 = t8n; h8a = h8an; h8b = h8bn;
        __syncthreads();
        buf ^= 1;
    }

    float* O = out + (((size_t)(b * S_ + i0 + 2 * w)) * S_ + jb * 16) * NOUT;
#pragma unroll
    for (int q = 0; q < 2; q++)
#pragma unroll
        for (int f = 0; f < 6; f++)
#pragma unroll
            for (int e = 0; e < 4; e++) {
                int j = lkq * 4 + e;
                O[(size_t)q * S_ * NOUT + (size_t)j * NOUT + f * 16 + lr] = acc[q][f][e] + b2v[f];
            }
}

extern "C" void kernel_launch(void* const* d_in, const int* in_sizes, int n_in,
                              void* d_out, int out_size, void* d_ws, size_t ws_size,
                              hipStream_t stream) {
    const float* x  = (const float*)d_in[0];   // [4][128][768]
    const float* W1 = (const float*)d_in[1];   // [1536][2304]
    const float* b1 = (const float*)d_in[2];   // [2304]
    const float* W2 = (const float*)d_in[3];   // [2304][96]
    const float* b2 = (const float*)d_in[4];   // [96]
    float* out = (float*)d_out;

    char* ws = (char*)d_ws;
    unsigned short* xb    = (unsigned short*)(ws);              //  512*768   bf16
    unsigned short* w2f   = (unsigned short*)(ws);              //  72*6*64*8 bf16 (overlays xb; written after gemm1)
    unsigned short* w1t   = (unsigned short*)(ws +   786432);   // 4608*768   bf16
    unsigned short* w2t   = (unsigned short*)(ws +  7864320);   //   96*2304  bf16
    unsigned short* headb = (unsigned short*)(ws +  8306688);   //  512*2304  bf16
    unsigned short* tailb = (unsigned short*)(ws + 10665984);   //  512*2304  bf16
    // total ws use: 13,025,280 bytes

    hipLaunchKernelGGL(k_cvt_x, dim3(384), dim3(256), 0, stream,
                       (const float4*)x, (ushort4*)xb);
    hipLaunchKernelGGL(k_transpose, dim3(72, 24, 2), dim3(256), 0, stream,
                       W1, w1t, H_, K3, (long)H_ * K3, (long)K3 * H_);
    hipLaunchKernelGGL(k_transpose, dim3(3, 72, 1), dim3(256), 0, stream,
                       W2, w2t, K3, NOUT, 0L, 0L);
    hipLaunchKernelGGL(k_gemm1, dim3(36, 4), dim3(256), 0, stream,
                       xb, w1t, b1, headb, tailb);
    // pack W2 frags AFTER gemm1 (w2f overlays xb, which gemm1 reads)
    hipLaunchKernelGGL(k_pack_w2, dim3(108), dim3(256), 0, stream,
                       w2t, w2f);
    hipLaunchKernelGGL(k_pair, dim3(8, 16, 4), dim3(256), 0, stream,
                       headb, tailb, w2f, b2, out);
}